// Round 1
// baseline (648.812 us; speedup 1.0000x reference)
//
#include <hip/hip_runtime.h>
#include <math.h>

#define NN 8000
#define NE 80000
#define NP 6    // radial basis p
#define NR 6    // rbf r
#define NA 20   // angular terms
#define NC 9    // channel (3x3)
#define PAC (NP*NA*NC)   // 1080
#define CUT 5.5f
#define EPSV 1e-9f

__constant__ int   c_lx[NA]  = {0, 1,0,0, 2,1,1,0,0,0, 3,2,2,1,1,1,0,0,0,0};
__constant__ int   c_ly[NA]  = {0, 0,1,0, 0,1,0,2,1,0, 0,1,0,2,1,0,3,2,1,0};
__constant__ int   c_lz[NA]  = {0, 0,0,1, 0,0,1,0,1,2, 0,0,1,0,1,2,0,1,2,3};
__constant__ int   c_ls[NA]  = {0, 1,1,1, 2,2,2,2,2,2, 3,3,3,3,3,3,3,3,3,3};
__constant__ float c_pref[NA]= {1.f, 1.f,1.f,1.f, 1.f,2.f,2.f,1.f,2.f,1.f,
                                1.f,3.f,3.f,3.f,6.f,3.f,1.f,3.f,3.f,1.f};

__device__ __forceinline__ int spec_of(int z) { return z == 1 ? 0 : (z == 6 ? 1 : 2); }

// One block per edge. Computes per-edge basis, scatters 1080 values into A0[receiver].
__global__ __launch_bounds__(256) void edge_scatter(
    const float* __restrict__ pos, const int* __restrict__ atnum,
    const int* __restrict__ ei, const float* __restrict__ shifts,
    const float* __restrict__ embW, const float* __restrict__ radW,
    float* __restrict__ A0, float* __restrict__ fcb)
{
    const int e = blockIdx.x;
    const int tid = threadIdx.x;
    const int s = ei[e];
    const int r = ei[NE + e];

    const float dx = pos[r*3+0] - pos[s*3+0] + shifts[e*3+0];
    const float dy = pos[r*3+1] - pos[s*3+1] + shifts[e*3+1];
    const float dz = pos[r*3+2] - pos[s*3+2] + shifts[e*3+2];
    const float len = sqrtf(dx*dx + dy*dy + dz*dz);
    const float inv = 1.f / (len + EPSV);
    const float ux = dx*inv, uy = dy*inv, uz = dz*inv;

    const float u  = len / CUT;
    const float u2 = u*u;
    const float u6 = u2*u2*u2;
    const float fcut = (u < 1.f) ? (1.f - 28.f*u6 + 48.f*u6*u - 21.f*u6*u2) : 0.f;
    if (tid == 0) fcb[e] = fcut;
    if (fcut == 0.f) return;   // uniform across block; all contributions are exactly 0

    __shared__ float sRad[NR];
    __shared__ float sRl[4*NP];
    __shared__ float sAng[NA];
    __shared__ float sEnc[NC];

    if (tid < NR) {
        const float nn = (float)(tid + 1);
        sRad[tid] = sqrtf(2.f/CUT) * sinf(nn * (float)M_PI * len / CUT) * inv;
    }
    if (tid >= 32 && tid < 32 + NA) {
        const int a = tid - 32;
        float px[4] = {1.f, ux, ux*ux, ux*ux*ux};
        float py[4] = {1.f, uy, uy*uy, uy*uy*uy};
        float pz[4] = {1.f, uz, uz*uz, uz*uz*uz};
        sAng[a] = px[c_lx[a]] * py[c_ly[a]] * pz[c_lz[a]];
    }
    if (tid >= 64 && tid < 64 + NC) {
        const int c = tid - 64;
        const int i = c / 3, j = c % 3;
        sEnc[c] = embW[spec_of(atnum[s])*3 + i] * embW[spec_of(atnum[r])*3 + j];
    }
    __syncthreads();
    if (tid < 4*NP) {
        const int l = tid / NP, p = tid % NP;
        float acc = 0.f;
        #pragma unroll
        for (int rr = 0; rr < NR; ++rr) acc += sRad[rr] * radW[l*NR*NP + rr*NP + p];
        sRl[tid] = fcut * acc;
    }
    __syncthreads();

    float* dst = A0 + (size_t)r * PAC;
    for (int i = tid; i < PAC; i += blockDim.x) {
        const int p   = i / (NA*NC);
        const int rem = i % (NA*NC);
        const int a   = rem / NC;
        const int c   = rem % NC;
        atomicAdd(&dst[i], sRl[c_ls[a]*NP + p] * sAng[a] * sEnc[c]);
    }
}

// One block per edge: agg[recv] += A0[send] * fcut(e)
__global__ __launch_bounds__(256) void mp_scatter(
    const int* __restrict__ ei, const float* __restrict__ fcb,
    const float* __restrict__ A0, float* __restrict__ A1)
{
    const int e = blockIdx.x;
    const float fc = fcb[e];
    if (fc == 0.f) return;
    const int s = ei[e];
    const int r = ei[NE + e];
    const float* __restrict__ src = A0 + (size_t)s * PAC;
    float* __restrict__ dst = A1 + (size_t)r * PAC;
    for (int i = threadIdx.x; i < PAC; i += blockDim.x)
        atomicAdd(&dst[i], src[i] * fc);
}

// Thread per (n,p,c): symmetrize both feature sets, write output (n,6,5,9,2)
__global__ __launch_bounds__(256) void finalize(
    const float* __restrict__ A0, const float* __restrict__ Agg,
    const float* __restrict__ memc, float* __restrict__ out)
{
    const int idx = blockIdx.x * blockDim.x + threadIdx.x;
    if (idx >= NN*NP*NC) return;
    const int c = idx % NC;
    const int t = idx / NC;
    const int p = t % NP;
    const int n = t / NP;

    const float mc  = memc[0];
    const float mpn = 0.3162277660168379f;  // 1/sqrt(10)

    const float* a0 = A0  + (size_t)n*PAC + p*(NA*NC) + c;
    const float* ag = Agg + (size_t)n*PAC + p*(NA*NC) + c;

    float f0[NA], f1[NA];
    #pragma unroll
    for (int a = 0; a < NA; ++a) {
        const float v0 = a0[a*NC];
        f0[a] = v0;
        f1[a] = mc * v0 + mpn * ag[a*NC];
    }
    float b20[4] = {0.f,0.f,0.f,0.f};
    float b21[4] = {0.f,0.f,0.f,0.f};
    #pragma unroll
    for (int a = 0; a < NA; ++a) {
        const int l = c_ls[a];
        const float pr = c_pref[a];
        b20[l] += pr * f0[a] * f0[a];
        b21[l] += pr * f1[a] * f1[a];
    }

    // out[n][p][lp][c][t] strides: n:540, p:90, lp:18, c:2, t:1
    const size_t base = (size_t)n*540 + (size_t)p*90 + (size_t)c*2;
    out[base + 0]  = f0[0];
    out[base + 1]  = f1[0];
    #pragma unroll
    for (int l = 0; l < 4; ++l) {
        out[base + (size_t)(l+1)*18 + 0] = b20[l];
        out[base + (size_t)(l+1)*18 + 1] = b21[l];
    }
}

extern "C" void kernel_launch(void* const* d_in, const int* in_sizes, int n_in,
                              void* d_out, int out_size, void* d_ws, size_t ws_size,
                              hipStream_t stream) {
    const float* pos    = (const float*)d_in[0];
    const int*   atnum  = (const int*)d_in[1];
    const int*   ei     = (const int*)d_in[2];
    const float* shifts = (const float*)d_in[3];
    const float* embW   = (const float*)d_in[4];
    const float* radW   = (const float*)d_in[5];
    const float* memc   = (const float*)d_in[6];
    float* out = (float*)d_out;

    float* A0  = (float*)d_ws;
    float* A1  = A0 + (size_t)NN * PAC;
    float* fcb = A1 + (size_t)NN * PAC;

    hipMemsetAsync(A0, 0, (size_t)2 * NN * PAC * sizeof(float), stream);

    edge_scatter<<<NE, 256, 0, stream>>>(pos, atnum, ei, shifts, embW, radW, A0, fcb);
    mp_scatter<<<NE, 256, 0, stream>>>(ei, fcb, A0, A1);
    finalize<<<(NN*NP*NC + 255)/256, 256, 0, stream>>>(A0, A1, memc, out);
}

// Round 2
// 199.303 us; speedup vs baseline: 3.2554x; 3.2554x over previous
//
#include <hip/hip_runtime.h>
#include <math.h>

#define NN 8000
#define NE 80000
#define NP 6
#define NR 6
#define NA 20
#define NC 9
#define PAC (NP*NA*NC)   // 1080
#define ED 56            // padded per-edge factor size: Rl[24] ang[20] enc[9] pad[3]
#define CUT 5.5f
#define EPSV 1e-9f

__constant__ int   c_lx[NA]  = {0, 1,0,0, 2,1,1,0,0,0, 3,2,2,1,1,1,0,0,0,0};
__constant__ int   c_ly[NA]  = {0, 0,1,0, 0,1,0,2,1,0, 0,1,0,2,1,0,3,2,1,0};
__constant__ int   c_lz[NA]  = {0, 0,0,1, 0,0,1,0,1,2, 0,0,1,0,1,2,0,1,2,3};
__constant__ int   c_ls[NA]  = {0, 1,1,1, 2,2,2,2,2,2, 3,3,3,3,3,3,3,3,3,3};
__constant__ float c_pref[NA]= {1.f, 1.f,1.f,1.f, 1.f,2.f,2.f,1.f,2.f,1.f,
                                1.f,3.f,3.f,3.f,6.f,3.f,1.f,3.f,3.f,1.f};

__device__ __forceinline__ int spec_of(int z) { return z == 1 ? 0 : (z == 6 ? 1 : 2); }

// ---------- 1. per-edge factorized basis: Rl[4*6], ang[20], enc[9] ----------
__global__ __launch_bounds__(256) void edge_basis(
    const float* __restrict__ pos, const int* __restrict__ atnum,
    const int* __restrict__ ei, const float* __restrict__ shifts,
    const float* __restrict__ embW, const float* __restrict__ radW,
    float* __restrict__ edat, float* __restrict__ fcb)
{
    const int e = blockIdx.x * blockDim.x + threadIdx.x;
    if (e >= NE) return;
    const int s = ei[e];
    const int r = ei[NE + e];

    const float dx = pos[r*3+0] - pos[s*3+0] + shifts[e*3+0];
    const float dy = pos[r*3+1] - pos[s*3+1] + shifts[e*3+1];
    const float dz = pos[r*3+2] - pos[s*3+2] + shifts[e*3+2];
    const float len = sqrtf(dx*dx + dy*dy + dz*dz);
    const float inv = 1.f / (len + EPSV);
    const float ux = dx*inv, uy = dy*inv, uz = dz*inv;

    const float u  = len / CUT;
    const float u2 = u*u;
    const float u6 = u2*u2*u2;
    const float fcut = (u < 1.f) ? (1.f - 28.f*u6 + 48.f*u6*u - 21.f*u6*u2) : 0.f;
    fcb[e] = fcut;

    float* E = edat + (size_t)e * ED;

    float rad[NR];
    const float cr = sqrtf(2.f/CUT) * inv;
    #pragma unroll
    for (int rr = 0; rr < NR; ++rr)
        rad[rr] = cr * sinf((float)(rr+1) * (float)M_PI * len / CUT);

    #pragma unroll
    for (int l = 0; l < 4; ++l)
        #pragma unroll
        for (int p = 0; p < NP; ++p) {
            float acc = 0.f;
            #pragma unroll
            for (int rr = 0; rr < NR; ++rr) acc += rad[rr] * radW[l*NR*NP + rr*NP + p];
            E[l*NP + p] = fcut * acc;
        }

    {
        float px[4] = {1.f, ux, ux*ux, ux*ux*ux};
        float py[4] = {1.f, uy, uy*uy, uy*uy*uy};
        float pz[4] = {1.f, uz, uz*uz, uz*uz*uz};
        #pragma unroll
        for (int a = 0; a < NA; ++a)
            E[24 + a] = px[c_lx[a]] * py[c_ly[a]] * pz[c_lz[a]];
    }
    {
        const int ss = spec_of(atnum[s]), sr = spec_of(atnum[r]);
        #pragma unroll
        for (int c = 0; c < NC; ++c)
            E[44 + c] = embW[ss*3 + c/3] * embW[sr*3 + c%3];
    }
}

// ---------- 2. CSR build by receiver ----------
__global__ __launch_bounds__(256) void csr_hist(const int* __restrict__ ei, int* __restrict__ cnt)
{
    const int e = blockIdx.x * blockDim.x + threadIdx.x;
    if (e < NE) atomicAdd(&cnt[ei[NE + e]], 1);
}

__global__ __launch_bounds__(256) void csr_scan(const int* __restrict__ cnt,
                                               int* __restrict__ off, int* __restrict__ cur)
{
    __shared__ int s[256];
    __shared__ int carry;
    const int t = threadIdx.x;
    if (t == 0) carry = 0;
    __syncthreads();
    for (int base = 0; base < NN; base += 256) {
        const int idx = base + t;
        const int v = (idx < NN) ? cnt[idx] : 0;
        s[t] = v;
        __syncthreads();
        for (int ofs = 1; ofs < 256; ofs <<= 1) {
            int x = (t >= ofs) ? s[t - ofs] : 0;
            __syncthreads();
            s[t] += x;
            __syncthreads();
        }
        const int excl = s[t] - v;
        if (idx < NN) { off[idx] = carry + excl; cur[idx] = carry + excl; }
        const int tot = s[255];
        __syncthreads();
        if (t == 0) carry += tot;
        __syncthreads();
    }
    if (t == 0) off[NN] = NE;
}

__global__ __launch_bounds__(256) void csr_fill(const int* __restrict__ ei,
                                                int* __restrict__ cur, int* __restrict__ elist)
{
    const int e = blockIdx.x * blockDim.x + threadIdx.x;
    if (e >= NE) return;
    const int pos = atomicAdd(&cur[ei[NE + e]], 1);
    elist[pos] = e;
}

// ---------- 3. node-centric A0 accumulation (no atomics) ----------
__global__ __launch_bounds__(256) void node_accum(
    const float* __restrict__ edat, const int* __restrict__ off,
    const int* __restrict__ elist, float* __restrict__ A0)
{
    const int n = blockIdx.x;
    const int tid = threadIdx.x;

    // per-thread element indices: i = tid + 256*k
    int iR[5], iA[5], iC[5], nk = 0;
    #pragma unroll
    for (int k = 0; k < 5; ++k) {
        const int i = tid + 256*k;
        if (i < PAC) {
            const int p = i / (NA*NC);
            const int a = (i / NC) % NA;
            const int c = i % NC;
            iR[k] = c_ls[a]*NP + p;
            iA[k] = 24 + a;
            iC[k] = 44 + c;
            nk = k + 1;
        }
    }
    float acc[5] = {0.f,0.f,0.f,0.f,0.f};

    __shared__ float sE[4*ED];
    const int nstart = off[n], nend = off[n+1];
    for (int i0 = nstart; i0 < nend; i0 += 4) {
        const int nb = min(4, nend - i0);
        __syncthreads();
        if (tid < nb*ED) {
            const int b = tid / ED, f = tid % ED;
            sE[tid] = edat[(size_t)elist[i0 + b]*ED + f];
        }
        __syncthreads();
        for (int b = 0; b < nb; ++b) {
            const float* E = &sE[b*ED];
            #pragma unroll
            for (int k = 0; k < 5; ++k)
                if (k < nk) acc[k] += E[iR[k]] * E[iA[k]] * E[iC[k]];
        }
    }

    float* row = A0 + (size_t)n * PAC;
    #pragma unroll
    for (int k = 0; k < 5; ++k)
        if (k < nk) row[tid + 256*k] = acc[k];
}

// ---------- 4. fused MP aggregation + symmetrize + output ----------
__global__ __launch_bounds__(256) void node_mp_final(
    const float* __restrict__ A0, const int* __restrict__ ei,
    const float* __restrict__ fcb, const int* __restrict__ off,
    const int* __restrict__ elist, const float* __restrict__ memc,
    float* __restrict__ out)
{
    const int n = blockIdx.x;
    const int tid = threadIdx.x;

    float agg[5] = {0.f,0.f,0.f,0.f,0.f};
    const int nstart = off[n], nend = off[n+1];
    for (int idx = nstart; idx < nend; ++idx) {
        const int e = elist[idx];
        const float fc = fcb[e];
        const int s = ei[e];
        const float* __restrict__ row = A0 + (size_t)s * PAC;
        #pragma unroll
        for (int k = 0; k < 5; ++k) {
            const int i = tid + 256*k;
            if (i < PAC) agg[k] += fc * row[i];
        }
    }

    __shared__ float sA0[PAC];
    __shared__ float sA1[PAC];
    __shared__ float sOut[540];

    const float mc  = memc[0];
    const float mpn = 0.3162277660168379f;  // 1/sqrt(10)
    const float* __restrict__ rowN = A0 + (size_t)n * PAC;
    #pragma unroll
    for (int k = 0; k < 5; ++k) {
        const int i = tid + 256*k;
        if (i < PAC) {
            const float v0 = rowN[i];
            sA0[i] = v0;
            sA1[i] = mc * v0 + mpn * agg[k];
        }
    }
    __syncthreads();

    if (tid < NP*NC) {
        const int p = tid / NC, c = tid % NC;
        const int base = p*(NA*NC) + c;
        float b20[4] = {0.f,0.f,0.f,0.f};
        float b21[4] = {0.f,0.f,0.f,0.f};
        #pragma unroll
        for (int a = 0; a < NA; ++a) {
            const int l = c_ls[a];
            const float pr = c_pref[a];
            const float x0 = sA0[base + a*NC];
            const float x1 = sA1[base + a*NC];
            b20[l] += pr * x0 * x0;
            b21[l] += pr * x1 * x1;
        }
        const int ob = p*90 + c*2;
        sOut[ob]     = sA0[base];
        sOut[ob + 1] = sA1[base];
        #pragma unroll
        for (int l = 0; l < 4; ++l) {
            sOut[ob + (l+1)*18]     = b20[l];
            sOut[ob + (l+1)*18 + 1] = b21[l];
        }
    }
    __syncthreads();

    float* __restrict__ o = out + (size_t)n * 540;
    for (int i = tid; i < 540; i += 256) o[i] = sOut[i];
}

extern "C" void kernel_launch(void* const* d_in, const int* in_sizes, int n_in,
                              void* d_out, int out_size, void* d_ws, size_t ws_size,
                              hipStream_t stream) {
    const float* pos    = (const float*)d_in[0];
    const int*   atnum  = (const int*)d_in[1];
    const int*   ei     = (const int*)d_in[2];
    const float* shifts = (const float*)d_in[3];
    const float* embW   = (const float*)d_in[4];
    const float* radW   = (const float*)d_in[5];
    const float* memc   = (const float*)d_in[6];
    float* out = (float*)d_out;

    float* edat = (float*)d_ws;                       // 80000*56
    float* A0   = edat + (size_t)NE * ED;             // 8000*1080
    float* fcb  = A0 + (size_t)NN * PAC;              // 80000
    int*   cnt  = (int*)(fcb + NE);                   // 8000
    int*   off  = cnt + NN;                           // 8001
    int*   cur  = off + NN + 1;                       // 8000
    int*   elist= cur + NN;                           // 80000

    hipMemsetAsync(cnt, 0, NN * sizeof(int), stream);

    edge_basis<<<(NE+255)/256, 256, 0, stream>>>(pos, atnum, ei, shifts, embW, radW, edat, fcb);
    csr_hist<<<(NE+255)/256, 256, 0, stream>>>(ei, cnt);
    csr_scan<<<1, 256, 0, stream>>>(cnt, off, cur);
    csr_fill<<<(NE+255)/256, 256, 0, stream>>>(ei, cur, elist);
    node_accum<<<NN, 256, 0, stream>>>(edat, off, elist, A0);
    node_mp_final<<<NN, 256, 0, stream>>>(A0, ei, fcb, off, elist, memc, out);
}

// Round 4
// 113.750 us; speedup vs baseline: 5.7039x; 1.7521x over previous
//
#include <hip/hip_runtime.h>
#include <math.h>

#define NN 8000
#define NE 80000
#define NP 6
#define NR 6
#define NA 20
#define NC 9
#define PAC (NP*NA*NC)   // 1080
#define ED 56            // padded per-edge factor row: Rl[24] ang[20] enc[9] pad[3]
#define CUT 5.5f
#define EPSV 1e-9f

__constant__ int   c_lx[NA]  = {0, 1,0,0, 2,1,1,0,0,0, 3,2,2,1,1,1,0,0,0,0};
__constant__ int   c_ly[NA]  = {0, 0,1,0, 0,1,0,2,1,0, 0,1,0,2,1,0,3,2,1,0};
__constant__ int   c_lz[NA]  = {0, 0,0,1, 0,0,1,0,1,2, 0,0,1,0,1,2,0,1,2,3};
__constant__ int   c_ls[NA]  = {0, 1,1,1, 2,2,2,2,2,2, 3,3,3,3,3,3,3,3,3,3};
__constant__ float c_pref[NA]= {1.f, 1.f,1.f,1.f, 1.f,2.f,2.f,1.f,2.f,1.f,
                                1.f,3.f,3.f,3.f,6.f,3.f,1.f,3.f,3.f,1.f};

__device__ __forceinline__ int spec_of(int z) { return z == 1 ? 0 : (z == 6 ? 1 : 2); }

__device__ __forceinline__ void fma4(float4& a, float f, const float4& v) {
    a.x = fmaf(f, v.x, a.x); a.y = fmaf(f, v.y, a.y);
    a.z = fmaf(f, v.z, a.z); a.w = fmaf(f, v.w, a.w);
}

// ---------- 1. per-edge factorized basis (+ receiver histogram) ----------
__global__ __launch_bounds__(256) void edge_basis(
    const float* __restrict__ pos, const int* __restrict__ atnum,
    const int* __restrict__ ei, const float* __restrict__ shifts,
    const float* __restrict__ embW, const float* __restrict__ radW,
    float* __restrict__ edat, float* __restrict__ fcb, int* __restrict__ cnt)
{
    const int e = blockIdx.x * blockDim.x + threadIdx.x;
    if (e >= NE) return;
    const int s = ei[e];
    const int r = ei[NE + e];

    const float dx = pos[r*3+0] - pos[s*3+0] + shifts[e*3+0];
    const float dy = pos[r*3+1] - pos[s*3+1] + shifts[e*3+1];
    const float dz = pos[r*3+2] - pos[s*3+2] + shifts[e*3+2];
    const float len = sqrtf(dx*dx + dy*dy + dz*dz);
    const float inv = 1.f / (len + EPSV);
    const float ux = dx*inv, uy = dy*inv, uz = dz*inv;

    const float u  = len / CUT;
    const float u2 = u*u;
    const float u6 = u2*u2*u2;
    const float fcut = (u < 1.f) ? (1.f - 28.f*u6 + 48.f*u6*u - 21.f*u6*u2) : 0.f;
    fcb[e] = fcut;
    atomicAdd(&cnt[r], 1);

    float E[ED];

    float rad[NR];
    const float cr = sqrtf(2.f/CUT) * inv;
    #pragma unroll
    for (int rr = 0; rr < NR; ++rr)
        rad[rr] = cr * sinf((float)(rr+1) * (float)M_PI * len / CUT);

    #pragma unroll
    for (int l = 0; l < 4; ++l)
        #pragma unroll
        for (int p = 0; p < NP; ++p) {
            float acc = 0.f;
            #pragma unroll
            for (int rr = 0; rr < NR; ++rr) acc += rad[rr] * radW[l*NR*NP + rr*NP + p];
            E[l*NP + p] = fcut * acc;
        }

    {
        float px[4] = {1.f, ux, ux*ux, ux*ux*ux};
        float py[4] = {1.f, uy, uy*uy, uy*uy*uy};
        float pz[4] = {1.f, uz, uz*uz, uz*uz*uz};
        #pragma unroll
        for (int a = 0; a < NA; ++a)
            E[24 + a] = px[c_lx[a]] * py[c_ly[a]] * pz[c_lz[a]];
    }
    {
        const int ss = spec_of(atnum[s]), sr = spec_of(atnum[r]);
        #pragma unroll
        for (int c = 0; c < NC; ++c)
            E[44 + c] = embW[ss*3 + c/3] * embW[sr*3 + c%3];
    }
    E[53] = 0.f; E[54] = 0.f; E[55] = 0.f;

    float4* __restrict__ E4 = (float4*)(edat + (size_t)e * ED);
    #pragma unroll
    for (int f = 0; f < 14; ++f)
        E4[f] = make_float4(E[4*f], E[4*f+1], E[4*f+2], E[4*f+3]);
}

// ---------- 2. exclusive scan of counts (single block, 1024 thr, shuffle) ----------
__global__ __launch_bounds__(1024) void csr_scan(const int* __restrict__ cnt,
                                                 int* __restrict__ off, int* __restrict__ cur)
{
    const int t = threadIdx.x;
    const int base = t * 8;
    int v[8]; int sum = 0;
    #pragma unroll
    for (int j = 0; j < 8; ++j) {
        v[j] = (base + j < NN) ? cnt[base + j] : 0;
        sum += v[j];
    }
    const int lane = t & 63, w = t >> 6;   // 16 waves
    int x = sum;
    #pragma unroll
    for (int d = 1; d < 64; d <<= 1) {
        int y = __shfl_up(x, d);
        if (lane >= d) x += y;
    }
    __shared__ int wsum[16];
    if (lane == 63) wsum[w] = x;
    __syncthreads();
    if (t < 64) {
        int y = (t < 16) ? wsum[t] : 0;
        #pragma unroll
        for (int d = 1; d < 16; d <<= 1) {
            int z = __shfl_up(y, d);
            if (lane >= d) y += z;
        }
        if (t < 16) wsum[t] = y;
    }
    __syncthreads();
    int excl = ((w > 0) ? wsum[w - 1] : 0) + (x - sum);
    #pragma unroll
    for (int j = 0; j < 8; ++j) {
        if (base + j < NN) { off[base + j] = excl; cur[base + j] = excl; }
        excl += v[j];
    }
    if (t == 0) off[NN] = NE;
}

// ---------- 3. CSR fill: edge id + (sender, fc) packed per CSR slot ----------
__global__ __launch_bounds__(256) void csr_fill(
    const int* __restrict__ ei, const float* __restrict__ fcb,
    int* __restrict__ cur, int* __restrict__ elist,
    int* __restrict__ slist, float* __restrict__ fclist)
{
    const int e = blockIdx.x * blockDim.x + threadIdx.x;
    if (e >= NE) return;
    const int pos = atomicAdd(&cur[ei[NE + e]], 1);
    elist[pos]  = e;
    slist[pos]  = ei[e];
    fclist[pos] = fcb[e];
}

// ---------- 4. node-centric A0 accumulation: thread = (p,a) pair ----------
#define EB 16
__global__ __launch_bounds__(256) void node_accum(
    const float* __restrict__ edat, const int* __restrict__ off,
    const int* __restrict__ elist, float* __restrict__ A0)
{
    const int n = blockIdx.x;
    const int tid = threadIdx.x;
    // 120 active threads: tid = p*NA + a  (p<6, a<20), each produces 9 c-values
    const bool act = (tid < NP * NA);
    const int p = tid / NA, a = tid % NA;
    const int l = (a >= 1) + (a >= 4) + (a >= 10);
    const int iR = l*NP + p;
    const int iA = 24 + a;

    float acc[NC];
    #pragma unroll
    for (int c = 0; c < NC; ++c) acc[c] = 0.f;

    __shared__ float4 sE4[EB * 14];
    float* sE = (float*)sE4;

    const int st = off[n], en = off[n+1];
    for (int i0 = st; i0 < en; i0 += EB) {
        const int nb = min(EB, en - i0);
        __syncthreads();
        for (int q = tid; q < nb * 14; q += 256) {
            const int b = q / 14, f = q % 14;
            sE4[q] = ((const float4*)(edat + (size_t)elist[i0 + b] * ED))[f];
        }
        __syncthreads();
        if (act) {
            for (int b = 0; b < nb; ++b) {
                const float* E = &sE[b * ED];
                const float ra = E[iR] * E[iA];
                #pragma unroll
                for (int c = 0; c < NC; ++c) acc[c] = fmaf(ra, E[44 + c], acc[c]);
            }
        }
    }
    if (act) {
        float* row = A0 + (size_t)n * PAC + tid * NC;
        #pragma unroll
        for (int c = 0; c < NC; ++c) row[c] = acc[c];
    }
}

// ---------- 5. fused MP gather + symmetrize + output ----------
__global__ __launch_bounds__(256) void node_mp_final(
    const float* __restrict__ A0,
    const int* __restrict__ slist, const float* __restrict__ fclist,
    const int* __restrict__ off, const float* __restrict__ memc,
    float* __restrict__ out)
{
    const int n = blockIdx.x;
    const int tid = threadIdx.x;

    __shared__ int   sS[256];
    __shared__ float sF[256];
    __shared__ float sA[2 * PAC];     // [0,1080): A0_n  [1080,2160): A1_n
    __shared__ float sOut[544];

    const int st = off[n], en = off[n+1];
    const int q0 = tid, q1 = tid + 256;          // float4 row indices (270 total)
    float4 acc0 = {0,0,0,0}, acc1 = {0,0,0,0};

    for (int b0 = st; b0 < en; b0 += 256) {
        const int nb = min(256, en - b0);
        __syncthreads();
        if (tid < nb) { sS[tid] = slist[b0 + tid]; sF[tid] = fclist[b0 + tid]; }
        __syncthreads();
        int j = 0;
        for (; j + 4 <= nb; j += 4) {
            const float4* r0 = (const float4*)(A0 + (size_t)sS[j+0] * PAC);
            const float4* r1 = (const float4*)(A0 + (size_t)sS[j+1] * PAC);
            const float4* r2 = (const float4*)(A0 + (size_t)sS[j+2] * PAC);
            const float4* r3 = (const float4*)(A0 + (size_t)sS[j+3] * PAC);
            const float f0 = sF[j+0], f1 = sF[j+1], f2 = sF[j+2], f3 = sF[j+3];
            float4 v0 = r0[q0], v1 = r1[q0], v2 = r2[q0], v3 = r3[q0];
            fma4(acc0, f0, v0); fma4(acc0, f1, v1);
            fma4(acc0, f2, v2); fma4(acc0, f3, v3);
            if (tid < 14) {
                float4 w0 = r0[q1], w1 = r1[q1], w2 = r2[q1], w3 = r3[q1];
                fma4(acc1, f0, w0); fma4(acc1, f1, w1);
                fma4(acc1, f2, w2); fma4(acc1, f3, w3);
            }
        }
        for (; j < nb; ++j) {
            const float4* r0 = (const float4*)(A0 + (size_t)sS[j] * PAC);
            const float f0 = sF[j];
            fma4(acc0, f0, r0[q0]);
            if (tid < 14) fma4(acc1, f0, r0[q1]);
        }
    }

    const float mc  = memc[0];
    const float mpn = 0.3162277660168379f;  // 1/sqrt(10)
    const float4* __restrict__ rowN = (const float4*)(A0 + (size_t)n * PAC);
    {
        float4 v = rowN[q0];
        float4 a1;
        a1.x = fmaf(mc, v.x, mpn * acc0.x);
        a1.y = fmaf(mc, v.y, mpn * acc0.y);
        a1.z = fmaf(mc, v.z, mpn * acc0.z);
        a1.w = fmaf(mc, v.w, mpn * acc0.w);
        ((float4*)sA)[q0] = v;
        ((float4*)(sA + PAC))[q0] = a1;
        if (tid < 14) {
            float4 v2 = rowN[q1];
            float4 b1;
            b1.x = fmaf(mc, v2.x, mpn * acc1.x);
            b1.y = fmaf(mc, v2.y, mpn * acc1.y);
            b1.z = fmaf(mc, v2.z, mpn * acc1.z);
            b1.w = fmaf(mc, v2.w, mpn * acc1.w);
            ((float4*)sA)[q1] = v2;
            ((float4*)(sA + PAC))[q1] = b1;
        }
    }
    __syncthreads();

    if (tid < NP * NC) {
        const int p = tid / NC, c = tid % NC;
        const int base = p * (NA * NC) + c;
        float b20[4] = {0.f,0.f,0.f,0.f};
        float b21[4] = {0.f,0.f,0.f,0.f};
        #pragma unroll
        for (int a = 0; a < NA; ++a) {
            const int ll = c_ls[a];
            const float pr = c_pref[a];
            const float x0 = sA[base + a*NC];
            const float x1 = sA[PAC + base + a*NC];
            b20[ll] = fmaf(pr * x0, x0, b20[ll]);
            b21[ll] = fmaf(pr * x1, x1, b21[ll]);
        }
        const int ob = p*90 + c*2;
        sOut[ob]     = sA[base];
        sOut[ob + 1] = sA[PAC + base];
        #pragma unroll
        for (int ll = 0; ll < 4; ++ll) {
            sOut[ob + (ll+1)*18]     = b20[ll];
            sOut[ob + (ll+1)*18 + 1] = b21[ll];
        }
    }
    __syncthreads();

    float4* __restrict__ o4 = (float4*)(out + (size_t)n * 540);
    if (tid < 135) o4[tid] = ((const float4*)sOut)[tid];
}

extern "C" void kernel_launch(void* const* d_in, const int* in_sizes, int n_in,
                              void* d_out, int out_size, void* d_ws, size_t ws_size,
                              hipStream_t stream) {
    const float* pos    = (const float*)d_in[0];
    const int*   atnum  = (const int*)d_in[1];
    const int*   ei     = (const int*)d_in[2];
    const float* shifts = (const float*)d_in[3];
    const float* embW   = (const float*)d_in[4];
    const float* radW   = (const float*)d_in[5];
    const float* memc   = (const float*)d_in[6];
    float* out = (float*)d_out;

    float* edat  = (float*)d_ws;                      // NE*56
    float* A0    = edat + (size_t)NE * ED;            // NN*1080
    float* fcb   = A0 + (size_t)NN * PAC;             // NE
    float* fclist= fcb + NE;                          // NE
    int*   cnt   = (int*)(fclist + NE);               // NN
    int*   off   = cnt + NN;                          // NN+1
    int*   cur   = off + NN + 1;                      // NN
    int*   elist = cur + NN;                          // NE
    int*   slist = elist + NE;                        // NE

    hipMemsetAsync(cnt, 0, NN * sizeof(int), stream);

    edge_basis<<<(NE+255)/256, 256, 0, stream>>>(pos, atnum, ei, shifts, embW, radW, edat, fcb, cnt);
    csr_scan<<<1, 1024, 0, stream>>>(cnt, off, cur);
    csr_fill<<<(NE+255)/256, 256, 0, stream>>>(ei, fcb, cur, elist, slist, fclist);
    node_accum<<<NN, 256, 0, stream>>>(edat, off, elist, A0);
    node_mp_final<<<NN, 256, 0, stream>>>(A0, slist, fclist, off, memc, out);
}

// Round 5
// 90.742 us; speedup vs baseline: 7.1501x; 1.2536x over previous
//
#include <hip/hip_runtime.h>
#include <math.h>

#define NN 8000
#define NE 80000
#define NP 6
#define NR 6
#define NA 20
#define NC 9
#define PAC (NP*NA*NC)   // 1080
#define EDW 28           // per-edge packed row: 56 bf16 = 28 uints (112 B)
#define CUT 5.5f
#define EPSV 1e-9f

__constant__ int   c_lx[NA]  = {0, 1,0,0, 2,1,1,0,0,0, 3,2,2,1,1,1,0,0,0,0};
__constant__ int   c_ly[NA]  = {0, 0,1,0, 0,1,0,2,1,0, 0,1,0,2,1,0,3,2,1,0};
__constant__ int   c_lz[NA]  = {0, 0,0,1, 0,0,1,0,1,2, 0,0,1,0,1,2,0,1,2,3};
__constant__ int   c_ls[NA]  = {0, 1,1,1, 2,2,2,2,2,2, 3,3,3,3,3,3,3,3,3,3};
__constant__ float c_pref[NA]= {1.f, 1.f,1.f,1.f, 1.f,2.f,2.f,1.f,2.f,1.f,
                                1.f,3.f,3.f,3.f,6.f,3.f,1.f,3.f,3.f,1.f};

__device__ __forceinline__ int spec_of(int z) { return z == 1 ? 0 : (z == 6 ? 1 : 2); }

// pack two f32 -> one uint of 2 bf16 (RNE); element a in low half
__device__ __forceinline__ unsigned pk2(float a, float b) {
    unsigned ua = __float_as_uint(a);
    unsigned ub = __float_as_uint(b);
    ua += 0x7FFFu + ((ua >> 16) & 1u);
    ub += 0x7FFFu + ((ub >> 16) & 1u);
    return (ua >> 16) | (ub & 0xFFFF0000u);
}
__device__ __forceinline__ float blo(unsigned u) { return __uint_as_float(u << 16); }
__device__ __forceinline__ float bhi(unsigned u) { return __uint_as_float(u & 0xFFFF0000u); }
// element f (bf16 index) from packed array
__device__ __forceinline__ float bfh(const unsigned* E, int f) {
    unsigned w = E[f >> 1];
    return (f & 1) ? bhi(w) : blo(w);
}

// ---------- 1. per-edge factorized basis, packed bf16 (+ receiver histogram) ----------
__global__ __launch_bounds__(256) void edge_basis(
    const float* __restrict__ pos, const int* __restrict__ atnum,
    const int* __restrict__ ei, const float* __restrict__ shifts,
    const float* __restrict__ embW, const float* __restrict__ radW,
    unsigned* __restrict__ edat, float* __restrict__ fcb, int* __restrict__ cnt)
{
    const int e = blockIdx.x * blockDim.x + threadIdx.x;
    if (e >= NE) return;
    const int s = ei[e];
    const int r = ei[NE + e];

    const float dx = pos[r*3+0] - pos[s*3+0] + shifts[e*3+0];
    const float dy = pos[r*3+1] - pos[s*3+1] + shifts[e*3+1];
    const float dz = pos[r*3+2] - pos[s*3+2] + shifts[e*3+2];
    const float len = sqrtf(dx*dx + dy*dy + dz*dz);
    const float inv = 1.f / (len + EPSV);
    const float ux = dx*inv, uy = dy*inv, uz = dz*inv;

    const float u  = len / CUT;
    const float u2 = u*u;
    const float u6 = u2*u2*u2;
    const float fcut = (u < 1.f) ? (1.f - 28.f*u6 + 48.f*u6*u - 21.f*u6*u2) : 0.f;
    fcb[e] = fcut;
    atomicAdd(&cnt[r], 1);

    float E[56];

    // rad[k] = sqrt(2/CUT)*sin((k+1)*pi*len/CUT)/len via sin recurrence
    float rad[NR];
    {
        const float th = len * (float)(M_PI / (double)CUT);
        float sc, cc;
        sincosf(th, &sc, &cc);
        const float cr = sqrtf(2.f/CUT) * inv;
        const float c2 = 2.f * cc;
        float skm1 = 0.f, sk = sc;
        #pragma unroll
        for (int k = 0; k < NR; ++k) {
            rad[k] = cr * sk;
            const float nx = c2 * sk - skm1;
            skm1 = sk; sk = nx;
        }
    }

    #pragma unroll
    for (int l = 0; l < 4; ++l)
        #pragma unroll
        for (int p = 0; p < NP; ++p) {
            float acc = 0.f;
            #pragma unroll
            for (int rr = 0; rr < NR; ++rr) acc += rad[rr] * radW[l*NR*NP + rr*NP + p];
            E[l*NP + p] = fcut * acc;
        }

    {
        float px[4] = {1.f, ux, ux*ux, ux*ux*ux};
        float py[4] = {1.f, uy, uy*uy, uy*uy*uy};
        float pz[4] = {1.f, uz, uz*uz, uz*uz*uz};
        #pragma unroll
        for (int a = 0; a < NA; ++a)
            E[24 + a] = px[c_lx[a]] * py[c_ly[a]] * pz[c_lz[a]];
    }
    {
        const int ss = spec_of(atnum[s]), sr = spec_of(atnum[r]);
        #pragma unroll
        for (int c = 0; c < NC; ++c)
            E[44 + c] = embW[ss*3 + c/3] * embW[sr*3 + c%3];
    }
    E[53] = 0.f; E[54] = 0.f; E[55] = 0.f;

    unsigned P[EDW];
    #pragma unroll
    for (int f = 0; f < EDW; ++f) P[f] = pk2(E[2*f], E[2*f+1]);

    uint4* __restrict__ E4 = (uint4*)(edat + (size_t)e * EDW);
    #pragma unroll
    for (int f = 0; f < 7; ++f)
        E4[f] = make_uint4(P[4*f], P[4*f+1], P[4*f+2], P[4*f+3]);
}

// ---------- 2. exclusive scan of counts (single block, 1024 thr, shuffle) ----------
__global__ __launch_bounds__(1024) void csr_scan(const int* __restrict__ cnt,
                                                 int* __restrict__ off, int* __restrict__ cur)
{
    const int t = threadIdx.x;
    const int base = t * 8;
    int v[8]; int sum = 0;
    #pragma unroll
    for (int j = 0; j < 8; ++j) {
        v[j] = (base + j < NN) ? cnt[base + j] : 0;
        sum += v[j];
    }
    const int lane = t & 63, w = t >> 6;   // 16 waves
    int x = sum;
    #pragma unroll
    for (int d = 1; d < 64; d <<= 1) {
        int y = __shfl_up(x, d);
        if (lane >= d) x += y;
    }
    __shared__ int wsum[16];
    if (lane == 63) wsum[w] = x;
    __syncthreads();
    if (t < 64) {
        int y = (t < 16) ? wsum[t] : 0;
        #pragma unroll
        for (int d = 1; d < 16; d <<= 1) {
            int z = __shfl_up(y, d);
            if (lane >= d) y += z;
        }
        if (t < 16) wsum[t] = y;
    }
    __syncthreads();
    int excl = ((w > 0) ? wsum[w - 1] : 0) + (x - sum);
    #pragma unroll
    for (int j = 0; j < 8; ++j) {
        if (base + j < NN) { off[base + j] = excl; cur[base + j] = excl; }
        excl += v[j];
    }
    if (t == 0) off[NN] = NE;
}

// ---------- 3. CSR fill ----------
__global__ __launch_bounds__(256) void csr_fill(
    const int* __restrict__ ei, const float* __restrict__ fcb,
    int* __restrict__ cur, int* __restrict__ elist,
    int* __restrict__ slist, float* __restrict__ fclist)
{
    const int e = blockIdx.x * blockDim.x + threadIdx.x;
    if (e >= NE) return;
    const int pos = atomicAdd(&cur[ei[NE + e]], 1);
    elist[pos]  = e;
    slist[pos]  = ei[e];
    fclist[pos] = fcb[e];
}

// ---------- 4. node-centric A0 accumulation -> bf16 row ----------
#define EB 16
__global__ __launch_bounds__(128) void node_accum(
    const unsigned* __restrict__ edat, const int* __restrict__ off,
    const int* __restrict__ elist, unsigned short* __restrict__ A0h)
{
    const int n = blockIdx.x;
    const int tid = threadIdx.x;
    // 120 active threads: tid = p*NA + a
    const bool act = (tid < NP * NA);
    const int p = tid / NA, a = tid % NA;
    const int l = (a >= 1) + (a >= 4) + (a >= 10);
    const int iR = l*NP + p;
    const int iA = 48 + a;     // bf16 index 24+a -> packed bf16 idx 24+a ... (bf16 element index)
    // NOTE: bfh takes bf16 element index directly; Rl at [0,24), ang at [24,44), enc at [44,53)

    float acc[NC];
    #pragma unroll
    for (int c = 0; c < NC; ++c) acc[c] = 0.f;

    __shared__ uint4 sE4[EB * 7];
    const unsigned* sE = (const unsigned*)sE4;
    __shared__ __align__(16) float sRow[PAC];

    const int st = off[n], en = off[n+1];
    for (int i0 = st; i0 < en; i0 += EB) {
        const int nb = min(EB, en - i0);
        __syncthreads();
        for (int q = tid; q < nb * 7; q += 128) {
            const int b = q / 7, f = q % 7;
            sE4[q] = ((const uint4*)(edat + (size_t)elist[i0 + b] * EDW))[f];
        }
        __syncthreads();
        if (act) {
            for (int b = 0; b < nb; ++b) {
                const unsigned* E = &sE[b * EDW];
                const float ra = bfh(E, iR) * bfh(E, 24 + a);
                #pragma unroll
                for (int c = 0; c < NC; ++c) acc[c] = fmaf(ra, bfh(E, 44 + c), acc[c]);
            }
        }
    }
    if (act) {
        #pragma unroll
        for (int c = 0; c < NC; ++c) sRow[tid * NC + c] = acc[c];
    }
    __syncthreads();

    // pack 1080 floats -> 270 uint2 chunks; thread tid does chunks tid, tid+128 (+14 extra)
    uint2* __restrict__ row = (uint2*)(A0h + (size_t)n * PAC);
    #pragma unroll
    for (int k = 0; k < 3; ++k) {
        const int q = tid + 128 * k;
        if (q < 270) {
            const float* s4 = &sRow[4 * q];
            row[q] = make_uint2(pk2(s4[0], s4[1]), pk2(s4[2], s4[3]));
        }
    }
}

// ---------- 5. fused MP gather (bf16) + symmetrize + output ----------
__global__ __launch_bounds__(256) void node_mp_final(
    const unsigned short* __restrict__ A0h,
    const int* __restrict__ slist, const float* __restrict__ fclist,
    const int* __restrict__ off, const float* __restrict__ memc,
    float* __restrict__ out)
{
    const int n = blockIdx.x;
    const int tid = threadIdx.x;

    __shared__ int   sS[256];
    __shared__ float sF[256];
    __shared__ __align__(16) float sA[2 * PAC];   // [0,1080): A0_n  [1080,2160): A1_n
    __shared__ __align__(16) float sOut[544];

    const int st = off[n], en = off[n+1];
    const int q0 = tid, q1 = tid + 256;           // uint2 chunk ids (270 total)
    float4 acc0 = {0,0,0,0}, acc1 = {0,0,0,0};

    for (int b0 = st; b0 < en; b0 += 256) {
        const int nb = min(256, en - b0);
        __syncthreads();
        if (tid < nb) { sS[tid] = slist[b0 + tid]; sF[tid] = fclist[b0 + tid]; }
        __syncthreads();
        int j = 0;
        for (; j + 8 <= nb; j += 8) {
            uint2 v[8], w[8];
            #pragma unroll
            for (int k = 0; k < 8; ++k)
                v[k] = ((const uint2*)(A0h + (size_t)sS[j+k] * PAC))[q0];
            if (tid < 14) {
                #pragma unroll
                for (int k = 0; k < 8; ++k)
                    w[k] = ((const uint2*)(A0h + (size_t)sS[j+k] * PAC))[q1];
            }
            #pragma unroll
            for (int k = 0; k < 8; ++k) {
                const float f = sF[j+k];
                acc0.x = fmaf(f, blo(v[k].x), acc0.x);
                acc0.y = fmaf(f, bhi(v[k].x), acc0.y);
                acc0.z = fmaf(f, blo(v[k].y), acc0.z);
                acc0.w = fmaf(f, bhi(v[k].y), acc0.w);
                if (tid < 14) {
                    acc1.x = fmaf(f, blo(w[k].x), acc1.x);
                    acc1.y = fmaf(f, bhi(w[k].x), acc1.y);
                    acc1.z = fmaf(f, blo(w[k].y), acc1.z);
                    acc1.w = fmaf(f, bhi(w[k].y), acc1.w);
                }
            }
        }
        for (; j < nb; ++j) {
            const float f = sF[j];
            const uint2* rh = (const uint2*)(A0h + (size_t)sS[j] * PAC);
            uint2 v = rh[q0];
            acc0.x = fmaf(f, blo(v.x), acc0.x);
            acc0.y = fmaf(f, bhi(v.x), acc0.y);
            acc0.z = fmaf(f, blo(v.y), acc0.z);
            acc0.w = fmaf(f, bhi(v.y), acc0.w);
            if (tid < 14) {
                uint2 w = rh[q1];
                acc1.x = fmaf(f, blo(w.x), acc1.x);
                acc1.y = fmaf(f, bhi(w.x), acc1.y);
                acc1.z = fmaf(f, blo(w.y), acc1.z);
                acc1.w = fmaf(f, bhi(w.y), acc1.w);
            }
        }
    }

    const float mc  = memc[0];
    const float mpn = 0.3162277660168379f;  // 1/sqrt(10)
    const uint2* __restrict__ rowN = (const uint2*)(A0h + (size_t)n * PAC);
    {
        uint2 v = rowN[q0];
        const float x0 = blo(v.x), x1 = bhi(v.x), x2 = blo(v.y), x3 = bhi(v.y);
        ((float4*)sA)[q0] = make_float4(x0, x1, x2, x3);
        ((float4*)(sA + PAC))[q0] = make_float4(
            fmaf(mc, x0, mpn * acc0.x), fmaf(mc, x1, mpn * acc0.y),
            fmaf(mc, x2, mpn * acc0.z), fmaf(mc, x3, mpn * acc0.w));
        if (tid < 14) {
            uint2 w = rowN[q1];
            const float y0 = blo(w.x), y1 = bhi(w.x), y2 = blo(w.y), y3 = bhi(w.y);
            ((float4*)sA)[q1] = make_float4(y0, y1, y2, y3);
            ((float4*)(sA + PAC))[q1] = make_float4(
                fmaf(mc, y0, mpn * acc1.x), fmaf(mc, y1, mpn * acc1.y),
                fmaf(mc, y2, mpn * acc1.z), fmaf(mc, y3, mpn * acc1.w));
        }
    }
    __syncthreads();

    if (tid < NP * NC) {
        const int p = tid / NC, c = tid % NC;
        const int base = p * (NA * NC) + c;
        float b20[4] = {0.f,0.f,0.f,0.f};
        float b21[4] = {0.f,0.f,0.f,0.f};
        #pragma unroll
        for (int a = 0; a < NA; ++a) {
            const int ll = c_ls[a];
            const float pr = c_pref[a];
            const float x0 = sA[base + a*NC];
            const float x1 = sA[PAC + base + a*NC];
            b20[ll] = fmaf(pr * x0, x0, b20[ll]);
            b21[ll] = fmaf(pr * x1, x1, b21[ll]);
        }
        const int ob = p*90 + c*2;
        sOut[ob]     = sA[base];
        sOut[ob + 1] = sA[PAC + base];
        #pragma unroll
        for (int ll = 0; ll < 4; ++ll) {
            sOut[ob + (ll+1)*18]     = b20[ll];
            sOut[ob + (ll+1)*18 + 1] = b21[ll];
        }
    }
    __syncthreads();

    float4* __restrict__ o4 = (float4*)(out + (size_t)n * 540);
    if (tid < 135) o4[tid] = ((const float4*)sOut)[tid];
}

extern "C" void kernel_launch(void* const* d_in, const int* in_sizes, int n_in,
                              void* d_out, int out_size, void* d_ws, size_t ws_size,
                              hipStream_t stream) {
    const float* pos    = (const float*)d_in[0];
    const int*   atnum  = (const int*)d_in[1];
    const int*   ei     = (const int*)d_in[2];
    const float* shifts = (const float*)d_in[3];
    const float* embW   = (const float*)d_in[4];
    const float* radW   = (const float*)d_in[5];
    const float* memc   = (const float*)d_in[6];
    float* out = (float*)d_out;

    unsigned*       edat = (unsigned*)d_ws;                    // NE*28 uints  (8.96 MB)
    unsigned short* A0h  = (unsigned short*)(edat + (size_t)NE * EDW);  // NN*1080 bf16 (17.28 MB)
    float* fcb    = (float*)(A0h + (size_t)NN * PAC);          // NE
    float* fclist = fcb + NE;                                  // NE
    int*   cnt    = (int*)(fclist + NE);                       // NN
    int*   off    = cnt + NN;                                  // NN+1
    int*   cur    = off + NN + 1;                              // NN
    int*   elist  = cur + NN;                                  // NE
    int*   slist  = elist + NE;                                // NE

    hipMemsetAsync(cnt, 0, NN * sizeof(int), stream);

    edge_basis<<<(NE+255)/256, 256, 0, stream>>>(pos, atnum, ei, shifts, embW, radW, edat, fcb, cnt);
    csr_scan<<<1, 1024, 0, stream>>>(cnt, off, cur);
    csr_fill<<<(NE+255)/256, 256, 0, stream>>>(ei, fcb, cur, elist, slist, fclist);
    node_accum<<<NN, 128, 0, stream>>>(edat, off, elist, A0h);
    node_mp_final<<<NN, 256, 0, stream>>>(A0h, slist, fclist, off, memc, out);
}

// Round 6
// 90.415 us; speedup vs baseline: 7.1759x; 1.0036x over previous
//
#include <hip/hip_runtime.h>
#include <math.h>

#define NN 8000
#define NE 80000
#define NP 6
#define NR 6
#define NA 20
#define NC 9
#define PAC (NP*NA*NC)   // 1080
#define EDW 28           // per-edge packed row: 56 bf16 = 28 uints (112 B)
#define CUT 5.5f
#define EPSV 1e-9f

__constant__ int   c_lx[NA]  = {0, 1,0,0, 2,1,1,0,0,0, 3,2,2,1,1,1,0,0,0,0};
__constant__ int   c_ly[NA]  = {0, 0,1,0, 0,1,0,2,1,0, 0,1,0,2,1,0,3,2,1,0};
__constant__ int   c_lz[NA]  = {0, 0,0,1, 0,0,1,0,1,2, 0,0,1,0,1,2,0,1,2,3};
__constant__ int   c_ls[NA]  = {0, 1,1,1, 2,2,2,2,2,2, 3,3,3,3,3,3,3,3,3,3};
__constant__ float c_pref[NA]= {1.f, 1.f,1.f,1.f, 1.f,2.f,2.f,1.f,2.f,1.f,
                                1.f,3.f,3.f,3.f,6.f,3.f,1.f,3.f,3.f,1.f};

__device__ __forceinline__ int spec_of(int z) { return z == 1 ? 0 : (z == 6 ? 1 : 2); }

// pack two f32 -> one uint of 2 bf16 (RNE); element a in low half
__device__ __forceinline__ unsigned pk2(float a, float b) {
    unsigned ua = __float_as_uint(a);
    unsigned ub = __float_as_uint(b);
    ua += 0x7FFFu + ((ua >> 16) & 1u);
    ub += 0x7FFFu + ((ub >> 16) & 1u);
    return (ua >> 16) | (ub & 0xFFFF0000u);
}
__device__ __forceinline__ float blo(unsigned u) { return __uint_as_float(u << 16); }
__device__ __forceinline__ float bhi(unsigned u) { return __uint_as_float(u & 0xFFFF0000u); }
// element f (bf16 element index) from packed array
__device__ __forceinline__ float bfh(const unsigned* E, int f) {
    unsigned w = E[f >> 1];
    return (f & 1) ? bhi(w) : blo(w);
}

// ---------- 0. zero the histogram (replaces 46us runtime fillBuffer) ----------
__global__ __launch_bounds__(256) void zero_cnt(int* __restrict__ cnt)
{
    const int i = blockIdx.x * blockDim.x + threadIdx.x;
    if (i < NN) cnt[i] = 0;
}

// ---------- 1. per-edge factorized basis, packed bf16 (+ receiver histogram) ----------
__global__ __launch_bounds__(256) void edge_basis(
    const float* __restrict__ pos, const int* __restrict__ atnum,
    const int* __restrict__ ei, const float* __restrict__ shifts,
    const float* __restrict__ embW, const float* __restrict__ radW,
    unsigned* __restrict__ edat, float* __restrict__ fcb, int* __restrict__ cnt)
{
    const int e = blockIdx.x * blockDim.x + threadIdx.x;
    if (e >= NE) return;
    const int s = ei[e];
    const int r = ei[NE + e];

    const float dx = pos[r*3+0] - pos[s*3+0] + shifts[e*3+0];
    const float dy = pos[r*3+1] - pos[s*3+1] + shifts[e*3+1];
    const float dz = pos[r*3+2] - pos[s*3+2] + shifts[e*3+2];
    const float len = sqrtf(dx*dx + dy*dy + dz*dz);
    const float inv = 1.f / (len + EPSV);
    const float ux = dx*inv, uy = dy*inv, uz = dz*inv;

    const float u  = len / CUT;
    const float u2 = u*u;
    const float u6 = u2*u2*u2;
    const float fcut = (u < 1.f) ? (1.f - 28.f*u6 + 48.f*u6*u - 21.f*u6*u2) : 0.f;
    fcb[e] = fcut;
    atomicAdd(&cnt[r], 1);

    float E[56];

    // rad[k] = sqrt(2/CUT)*sin((k+1)*pi*len/CUT)/len via sin recurrence
    float rad[NR];
    {
        const float th = len * (float)(M_PI / (double)CUT);
        float sc, cc;
        sincosf(th, &sc, &cc);
        const float cr = sqrtf(2.f/CUT) * inv;
        const float c2 = 2.f * cc;
        float skm1 = 0.f, sk = sc;
        #pragma unroll
        for (int k = 0; k < NR; ++k) {
            rad[k] = cr * sk;
            const float nx = c2 * sk - skm1;
            skm1 = sk; sk = nx;
        }
    }

    #pragma unroll
    for (int l = 0; l < 4; ++l)
        #pragma unroll
        for (int p = 0; p < NP; ++p) {
            float acc = 0.f;
            #pragma unroll
            for (int rr = 0; rr < NR; ++rr) acc += rad[rr] * radW[l*NR*NP + rr*NP + p];
            E[l*NP + p] = fcut * acc;
        }

    {
        float px[4] = {1.f, ux, ux*ux, ux*ux*ux};
        float py[4] = {1.f, uy, uy*uy, uy*uy*uy};
        float pz[4] = {1.f, uz, uz*uz, uz*uz*uz};
        #pragma unroll
        for (int a = 0; a < NA; ++a)
            E[24 + a] = px[c_lx[a]] * py[c_ly[a]] * pz[c_lz[a]];
    }
    {
        const int ss = spec_of(atnum[s]), sr = spec_of(atnum[r]);
        #pragma unroll
        for (int c = 0; c < NC; ++c)
            E[44 + c] = embW[ss*3 + c/3] * embW[sr*3 + c%3];
    }
    E[53] = 0.f; E[54] = 0.f; E[55] = 0.f;

    unsigned P[EDW];
    #pragma unroll
    for (int f = 0; f < EDW; ++f) P[f] = pk2(E[2*f], E[2*f+1]);

    uint4* __restrict__ E4 = (uint4*)(edat + (size_t)e * EDW);
    #pragma unroll
    for (int f = 0; f < 7; ++f)
        E4[f] = make_uint4(P[4*f], P[4*f+1], P[4*f+2], P[4*f+3]);
}

// ---------- 2. exclusive scan of counts (single block, 1024 thr, shuffle) ----------
__global__ __launch_bounds__(1024) void csr_scan(const int* __restrict__ cnt,
                                                 int* __restrict__ off, int* __restrict__ cur)
{
    const int t = threadIdx.x;
    const int base = t * 8;
    int v[8]; int sum = 0;
    #pragma unroll
    for (int j = 0; j < 8; ++j) {
        v[j] = (base + j < NN) ? cnt[base + j] : 0;
        sum += v[j];
    }
    const int lane = t & 63, w = t >> 6;   // 16 waves
    int x = sum;
    #pragma unroll
    for (int d = 1; d < 64; d <<= 1) {
        int y = __shfl_up(x, d);
        if (lane >= d) x += y;
    }
    __shared__ int wsum[16];
    if (lane == 63) wsum[w] = x;
    __syncthreads();
    if (t < 64) {
        int y = (t < 16) ? wsum[t] : 0;
        #pragma unroll
        for (int d = 1; d < 16; d <<= 1) {
            int z = __shfl_up(y, d);
            if (lane >= d) y += z;
        }
        if (t < 16) wsum[t] = y;
    }
    __syncthreads();
    int excl = ((w > 0) ? wsum[w - 1] : 0) + (x - sum);
    #pragma unroll
    for (int j = 0; j < 8; ++j) {
        if (base + j < NN) { off[base + j] = excl; cur[base + j] = excl; }
        excl += v[j];
    }
    if (t == 0) off[NN] = NE;
}

// ---------- 3. CSR fill ----------
__global__ __launch_bounds__(256) void csr_fill(
    const int* __restrict__ ei, const float* __restrict__ fcb,
    int* __restrict__ cur, int* __restrict__ elist,
    int* __restrict__ slist, float* __restrict__ fclist)
{
    const int e = blockIdx.x * blockDim.x + threadIdx.x;
    if (e >= NE) return;
    const int pos = atomicAdd(&cur[ei[NE + e]], 1);
    elist[pos]  = e;
    slist[pos]  = ei[e];
    fclist[pos] = fcb[e];
}

// ---------- 4. node-centric A0 accumulation -> bf16 row ----------
#define EB 16
__global__ __launch_bounds__(128) void node_accum(
    const unsigned* __restrict__ edat, const int* __restrict__ off,
    const int* __restrict__ elist, unsigned short* __restrict__ A0h)
{
    const int n = blockIdx.x;
    const int tid = threadIdx.x;
    // 120 active threads: tid = p*NA + a
    const bool act = (tid < NP * NA);
    const int p = tid / NA, a = tid % NA;
    const int l = (a >= 1) + (a >= 4) + (a >= 10);
    const int iR = l*NP + p;

    float acc[NC];
    #pragma unroll
    for (int c = 0; c < NC; ++c) acc[c] = 0.f;

    __shared__ uint4 sE4[EB * 7];
    const unsigned* sE = (const unsigned*)sE4;
    __shared__ __align__(16) float sRow[PAC];

    const int st = off[n], en = off[n+1];
    for (int i0 = st; i0 < en; i0 += EB) {
        const int nb = min(EB, en - i0);
        __syncthreads();
        for (int q = tid; q < nb * 7; q += 128) {
            const int b = q / 7, f = q % 7;
            sE4[q] = ((const uint4*)(edat + (size_t)elist[i0 + b] * EDW))[f];
        }
        __syncthreads();
        if (act) {
            for (int b = 0; b < nb; ++b) {
                const unsigned* E = &sE[b * EDW];
                const float ra = bfh(E, iR) * bfh(E, 24 + a);
                #pragma unroll
                for (int c = 0; c < NC; ++c) acc[c] = fmaf(ra, bfh(E, 44 + c), acc[c]);
            }
        }
    }
    if (act) {
        #pragma unroll
        for (int c = 0; c < NC; ++c) sRow[tid * NC + c] = acc[c];
    }
    __syncthreads();

    // pack 1080 floats -> 270 uint2 chunks
    uint2* __restrict__ row = (uint2*)(A0h + (size_t)n * PAC);
    #pragma unroll
    for (int k = 0; k < 3; ++k) {
        const int q = tid + 128 * k;
        if (q < 270) {
            const float* s4 = &sRow[4 * q];
            row[q] = make_uint2(pk2(s4[0], s4[1]), pk2(s4[2], s4[3]));
        }
    }
}

// ---------- 5. fused MP gather (bf16) + symmetrize + output ----------
__global__ __launch_bounds__(256) void node_mp_final(
    const unsigned short* __restrict__ A0h,
    const int* __restrict__ slist, const float* __restrict__ fclist,
    const int* __restrict__ off, const float* __restrict__ memc,
    float* __restrict__ out)
{
    const int n = blockIdx.x;
    const int tid = threadIdx.x;

    __shared__ int   sS[256];
    __shared__ float sF[256];
    __shared__ __align__(16) float sA[2 * PAC];   // [0,1080): A0_n  [1080,2160): A1_n
    __shared__ __align__(16) float sOut[544];

    const int st = off[n], en = off[n+1];
    const int q0 = tid, q1 = tid + 256;           // uint2 chunk ids (270 total)
    float4 acc0 = {0,0,0,0}, acc1 = {0,0,0,0};

    for (int b0 = st; b0 < en; b0 += 256) {
        const int nb = min(256, en - b0);
        __syncthreads();
        if (tid < nb) { sS[tid] = slist[b0 + tid]; sF[tid] = fclist[b0 + tid]; }
        __syncthreads();
        int j = 0;
        for (; j + 8 <= nb; j += 8) {
            uint2 v[8], w[8];
            #pragma unroll
            for (int k = 0; k < 8; ++k)
                v[k] = ((const uint2*)(A0h + (size_t)sS[j+k] * PAC))[q0];
            if (tid < 14) {
                #pragma unroll
                for (int k = 0; k < 8; ++k)
                    w[k] = ((const uint2*)(A0h + (size_t)sS[j+k] * PAC))[q1];
            }
            #pragma unroll
            for (int k = 0; k < 8; ++k) {
                const float f = sF[j+k];
                acc0.x = fmaf(f, blo(v[k].x), acc0.x);
                acc0.y = fmaf(f, bhi(v[k].x), acc0.y);
                acc0.z = fmaf(f, blo(v[k].y), acc0.z);
                acc0.w = fmaf(f, bhi(v[k].y), acc0.w);
                if (tid < 14) {
                    acc1.x = fmaf(f, blo(w[k].x), acc1.x);
                    acc1.y = fmaf(f, bhi(w[k].x), acc1.y);
                    acc1.z = fmaf(f, blo(w[k].y), acc1.z);
                    acc1.w = fmaf(f, bhi(w[k].y), acc1.w);
                }
            }
        }
        for (; j < nb; ++j) {
            const float f = sF[j];
            const uint2* rh = (const uint2*)(A0h + (size_t)sS[j] * PAC);
            uint2 v = rh[q0];
            acc0.x = fmaf(f, blo(v.x), acc0.x);
            acc0.y = fmaf(f, bhi(v.x), acc0.y);
            acc0.z = fmaf(f, blo(v.y), acc0.z);
            acc0.w = fmaf(f, bhi(v.y), acc0.w);
            if (tid < 14) {
                uint2 w = rh[q1];
                acc1.x = fmaf(f, blo(w.x), acc1.x);
                acc1.y = fmaf(f, bhi(w.x), acc1.y);
                acc1.z = fmaf(f, blo(w.y), acc1.z);
                acc1.w = fmaf(f, bhi(w.y), acc1.w);
            }
        }
    }

    const float mc  = memc[0];
    const float mpn = 0.3162277660168379f;  // 1/sqrt(10)
    const uint2* __restrict__ rowN = (const uint2*)(A0h + (size_t)n * PAC);
    {
        uint2 v = rowN[q0];
        const float x0 = blo(v.x), x1 = bhi(v.x), x2 = blo(v.y), x3 = bhi(v.y);
        ((float4*)sA)[q0] = make_float4(x0, x1, x2, x3);
        ((float4*)(sA + PAC))[q0] = make_float4(
            fmaf(mc, x0, mpn * acc0.x), fmaf(mc, x1, mpn * acc0.y),
            fmaf(mc, x2, mpn * acc0.z), fmaf(mc, x3, mpn * acc0.w));
        if (tid < 14) {
            uint2 w = rowN[q1];
            const float y0 = blo(w.x), y1 = bhi(w.x), y2 = blo(w.y), y3 = bhi(w.y);
            ((float4*)sA)[q1] = make_float4(y0, y1, y2, y3);
            ((float4*)(sA + PAC))[q1] = make_float4(
                fmaf(mc, y0, mpn * acc1.x), fmaf(mc, y1, mpn * acc1.y),
                fmaf(mc, y2, mpn * acc1.z), fmaf(mc, y3, mpn * acc1.w));
        }
    }
    __syncthreads();

    if (tid < NP * NC) {
        const int p = tid / NC, c = tid % NC;
        const int base = p * (NA * NC) + c;
        float b20[4] = {0.f,0.f,0.f,0.f};
        float b21[4] = {0.f,0.f,0.f,0.f};
        #pragma unroll
        for (int a = 0; a < NA; ++a) {
            const int ll = c_ls[a];
            const float pr = c_pref[a];
            const float x0 = sA[base + a*NC];
            const float x1 = sA[PAC + base + a*NC];
            b20[ll] = fmaf(pr * x0, x0, b20[ll]);
            b21[ll] = fmaf(pr * x1, x1, b21[ll]);
        }
        const int ob = p*90 + c*2;
        sOut[ob]     = sA[base];
        sOut[ob + 1] = sA[PAC + base];
        #pragma unroll
        for (int ll = 0; ll < 4; ++ll) {
            sOut[ob + (ll+1)*18]     = b20[ll];
            sOut[ob + (ll+1)*18 + 1] = b21[ll];
        }
    }
    __syncthreads();

    float4* __restrict__ o4 = (float4*)(out + (size_t)n * 540);
    if (tid < 135) o4[tid] = ((const float4*)sOut)[tid];
}

extern "C" void kernel_launch(void* const* d_in, const int* in_sizes, int n_in,
                              void* d_out, int out_size, void* d_ws, size_t ws_size,
                              hipStream_t stream) {
    const float* pos    = (const float*)d_in[0];
    const int*   atnum  = (const int*)d_in[1];
    const int*   ei     = (const int*)d_in[2];
    const float* shifts = (const float*)d_in[3];
    const float* embW   = (const float*)d_in[4];
    const float* radW   = (const float*)d_in[5];
    const float* memc   = (const float*)d_in[6];
    float* out = (float*)d_out;

    unsigned*       edat = (unsigned*)d_ws;                    // NE*28 uints  (8.96 MB)
    unsigned short* A0h  = (unsigned short*)(edat + (size_t)NE * EDW);  // NN*1080 bf16 (17.28 MB)
    float* fcb    = (float*)(A0h + (size_t)NN * PAC);          // NE
    float* fclist = fcb + NE;                                  // NE
    int*   cnt    = (int*)(fclist + NE);                       // NN
    int*   off    = cnt + NN;                                  // NN+1
    int*   cur    = off + NN + 1;                              // NN
    int*   elist  = cur + NN;                                  // NE
    int*   slist  = elist + NE;                                // NE

    zero_cnt<<<(NN+255)/256, 256, 0, stream>>>(cnt);
    edge_basis<<<(NE+255)/256, 256, 0, stream>>>(pos, atnum, ei, shifts, embW, radW, edat, fcb, cnt);
    csr_scan<<<1, 1024, 0, stream>>>(cnt, off, cur);
    csr_fill<<<(NE+255)/256, 256, 0, stream>>>(ei, fcb, cur, elist, slist, fclist);
    node_accum<<<NN, 128, 0, stream>>>(edat, off, elist, A0h);
    node_mp_final<<<NN, 256, 0, stream>>>(A0h, slist, fclist, off, memc, out);
}